// Round 10
// baseline (115.117 us; speedup 1.0000x reference)
//
#include <hip/hip_runtime.h>
#include <limits.h>
#include <stdint.h>

#define ALPHA 0.2f
#define HALFA 0.1f
static constexpr int N = 8192;
static constexpr int D = 128;
static constexpr int C = 512;
static constexpr int BT = 128;                    // tile edge (points per tile)
static constexpr int GR = D / 8;                  // 16 granules (half8) per row
static constexpr int SL = BT + 1;                 // padded row count per granule
static constexpr int MAXG = 48;                   // e-list capacity (mean 16, 8 sigma)
static constexpr int NB = N / BT;                 // 64 row/col panels
static constexpr int NT1T = 512;                  // term1 tiles: 8 class-panels x 64 j-tiles
static constexpr int NTRI = NB * (NB + 1) / 2;    // 2080 term2 triangle tiles
static constexpr int GRID = 768;                  // 3 blocks/CU x 256 CUs (VGPR 64, LDS 52.7K)

// Sentinels: EPAD must differ from DMASK — pad slot with ev==EPAD vs masked base DMASK
// must give |ev-DMASK| >= HALFA (R9 bug: EPAD==DMASK made u=0 -> +HALFA leak per slot).
#define DMASK 3.0e38f
#define EPAD  1.0e37f

using half8    = __attribute__((ext_vector_type(8))) _Float16;
using floatx16 = __attribute__((ext_vector_type(16))) float;

__device__ __forceinline__ floatx16 zerov() { floatx16 v = {0.f}; return v; }

__device__ __forceinline__ half8 cvt8(float4 v0, float4 v1) {
    half8 h;
    h[0] = (_Float16)v0.x; h[1] = (_Float16)v0.y; h[2] = (_Float16)v0.z; h[3] = (_Float16)v0.w;
    h[4] = (_Float16)v1.x; h[5] = (_Float16)v1.y; h[6] = (_Float16)v1.z; h[7] = (_Float16)v1.w;
    return h;
}

__device__ __forceinline__ float ss8(float4 v0, float4 v1) {
    return v0.x*v0.x + v0.y*v0.y + v0.z*v0.z + v0.w*v0.w
         + v1.x*v1.x + v1.y*v1.y + v1.z*v1.z + v1.w*v1.w;
}

// ---- k_prep: anchors + xh (fp16) + sq + ap + GLOBAL e-lists ---------------------------
// (pads of egrid are NOT initialized; k_main masks them via ecnt during the LDS copy)

__launch_bounds__(256)
__global__ void k_prep(const float* __restrict__ x, const int* __restrict__ labels,
                       _Float16* __restrict__ xh, float* __restrict__ sq,
                       int* __restrict__ anchorg, float* __restrict__ ap,
                       int* __restrict__ ecnt, float* __restrict__ egrid,
                       float* __restrict__ out) {
    __shared__ int sAnc[C];
    const int tid = threadIdx.x;
    if (blockIdx.x == 0 && tid == 0) out[0] = 0.f;
    for (int i = tid; i < C; i += 256) sAnc[i] = INT_MAX;
    __syncthreads();
    const int4* lab4 = (const int4*)labels;
    for (int t = tid; t < N / 4; t += 256) {
        int4 lv = lab4[t];
        int base = 4 * t;
        atomicMin(&sAnc[lv.x], base);
        atomicMin(&sAnc[lv.y], base + 1);
        atomicMin(&sAnc[lv.z], base + 2);
        atomicMin(&sAnc[lv.w], base + 3);
    }
    __syncthreads();
    if (tid < 2) {
        int c = blockIdx.x * 2 + tid;
        int a = sAnc[c];
        anchorg[c] = (a == INT_MAX) ? -1 : a;
    }

    const int r = blockIdx.x * 32 + (tid >> 3);
    const int sub = tid & 7;
    const float4* src = (const float4*)(x + (size_t)r * D) + sub * 4;
    half8* dst = (half8*)(xh + (size_t)r * D) + sub * 2;
    half8 hj[2];
    float ssj = 0.f;
#pragma unroll
    for (int i = 0; i < 2; ++i) {
        float4 v0 = src[2 * i], v1 = src[2 * i + 1];
        hj[i] = cvt8(v0, v1);
        dst[i] = hj[i];
        ssj += ss8(v0, v1);
    }
    ssj += __shfl_xor(ssj, 1); ssj += __shfl_xor(ssj, 2); ssj += __shfl_xor(ssj, 4);

    const int lab = labels[r];
    const int a = sAnc[lab];
    const float4* asrc = (const float4*)(x + (size_t)a * D) + sub * 4;
    float ssa = 0.f, dot = 0.f;
#pragma unroll
    for (int i = 0; i < 2; ++i) {
        float4 a0 = asrc[2 * i], a1 = asrc[2 * i + 1];
        half8 ha = cvt8(a0, a1);
        ssa += ss8(a0, a1);
#pragma unroll
        for (int e = 0; e < 8; ++e) dot = fmaf((float)ha[e], (float)hj[i][e], dot);
    }
    ssa += __shfl_xor(ssa, 1); ssa += __shfl_xor(ssa, 2); ssa += __shfl_xor(ssa, 4);
    dot += __shfl_xor(dot, 1); dot += __shfl_xor(dot, 2); dot += __shfl_xor(dot, 4);
    if (sub == 0) {
        float apv = ssa + ssj - 2.f * dot;
        sq[r] = ssj;
        ap[r] = apv;
        if (r != a) {   // append to the class e-list (anchor itself excluded)
            int slot = atomicAdd(&ecnt[lab], 1);
            if (slot < MAXG) egrid[(size_t)lab * MAXG + slot] = apv + HALFA;
        }
    }
}

// ---- k_main: 768 balanced blocks (3/CU exact) -----------------------------------------
// blocks 0..511:  1 term1 tile + term2 tiles [2b, 2b+2)          (4 work-units)
// blocks 512..735: term2 tiles [1024+(b-512)*4, +4)              (4 units)
// blocks 736..767: term2 tiles [1920+(b-736)*5, +5)              (5 units, diag-light rows)
// Contiguous triangle runs -> A-panel reuse, few seams. Inner loops identical to R8
// (which compiled to VGPR 64 -> 3 blocks/CU at 52.7 KB LDS).
// __launch_bounds__(512,2): proven no-spill point; do NOT raise the min-waves arg (R6!).

__launch_bounds__(512, 2)
__global__ void k_main(const _Float16* __restrict__ xh, const int* __restrict__ labels,
                       const int* __restrict__ anchor, const float* __restrict__ sq,
                       const float* __restrict__ ap, const int* __restrict__ ecnt,
                       const float* __restrict__ egrid, float* __restrict__ out) {
    __shared__ __align__(16) _Float16 BsH[GR * SL * 8];   // 33024 B, K-major [granule][row]
    __shared__ __align__(16) float sge[64 * MAXG];        // 12288 B e-lists
    __shared__ float4 rowE[BT];
    __shared__ float4 colE[2][BT];
    __shared__ int   sArow[64];
    __shared__ float sSqA[64];
    __shared__ int   sCnt[64];
    __shared__ float wsum[8];
    half8* Bs = (half8*)BsH;

    const int tid = threadIdx.x;
    const int lane = tid & 63, w = tid >> 6;
    const int m = lane & 31, q = lane >> 5;
    const int sg = tid & 15, sr0 = tid >> 4;   // staging: granule, row base
    float local = 0.f;
    int cnt = 0;                                // hinge slots evaluated (for +h*cnt)

    const int b = blockIdx.x;
    const bool hasT1 = (b < NT1T);
    // term1 tile coords
    const int c0 = (b >> 6) * 64, j1 = (b & 63) * BT;
    // term2 run [ts, te)
    int ts, te;
    if (b < 512)      { ts = 2 * b;                te = ts + 2; }
    else if (b < 736) { ts = 1024 + (b - 512) * 4; te = ts + 4; }
    else              { ts = 1920 + (b - 736) * 5; te = ts + 5; }

    half8 af[8], breg[4];
    floatx16 acc = zerov();

    if (hasT1) {
        // ============ phase 0: term1 meta + masked e-list copy + B/colE prefetch ============
        if (tid < 64) {
            int c = c0 + tid;
            int a = anchor[c];
            int ar = (a < 0) ? 0 : a;          // dummy (absent class has cnt 0)
            sArow[tid] = ar;
            sSqA[tid] = sq[ar];
            int n = ecnt[c];
            sCnt[tid] = (n > MAXG) ? MAXG : n;
        }
        {   // e-list copy with pad masking (egrid pads are uninitialized) -> EPAD
            const float4* srcv = (const float4*)(egrid + (size_t)c0 * MAXG);
            float4* dstv = (float4*)sge;
#pragma unroll
            for (int rep = 0; rep < 2; ++rep) {
                int idx = tid + rep * 512;
                if (idx < 64 * (MAXG / 4)) {
                    int cls = idx / (MAXG / 4);
                    int sb = (idx % (MAXG / 4)) * 4;
                    int n = ecnt[c0 + cls]; n = (n > MAXG) ? MAXG : n;
                    float4 v = srcv[idx];
                    v.x = (sb + 0 < n) ? v.x : EPAD;
                    v.y = (sb + 1 < n) ? v.y : EPAD;
                    v.z = (sb + 2 < n) ? v.z : EPAD;
                    v.w = (sb + 3 < n) ? v.w : EPAD;
                    dstv[idx] = v;
                }
            }
        }
#pragma unroll
        for (int i = 0; i < 4; ++i)
            breg[i] = *((const half8*)(xh + (size_t)(j1 + sr0 + 32 * i) * D) + sg);
        if (tid < BT) {
            int j = j1 + tid;
            colE[0][tid] = make_float4(sq[j], __int_as_float(labels[j]), 0.f, 0.f);
        }
        __syncthreads();

        // ============ phase 1: term1 MFMA ============
        {   // gathered anchor rows; 2 row-groups x 4 col-groups
            int arow = sArow[(w >> 2) * 32 + m];
            const half8* aptr = (const half8*)(xh + (size_t)arow * D) + q;
#pragma unroll
            for (int k = 0; k < 8; ++k) af[k] = aptr[2 * k];
        }
#pragma unroll
        for (int i = 0; i < 4; ++i)
            Bs[sg * SL + sr0 + 32 * i] = breg[i];
        __syncthreads();

#pragma unroll
        for (int k = 0; k < 8; ++k) {
            half8 b0 = Bs[(2 * k + q) * SL + (w & 3) * 32 + m];
            acc = __builtin_amdgcn_mfma_f32_32x32x16_f16(af[k], b0, acc, 0, 0, 0);
        }
    }

    // ============ phase 2: prefetch first term2 tile (all blocks) ============
    int br0 = 0;
    {
        int rem = ts;
        while (rem >= NB - br0) { rem -= NB - br0; ++br0; }
        int bc0 = br0 + rem;
        const half8* aptr = (const half8*)(xh + (size_t)(br0 * BT + (w >> 1) * 32 + m) * D) + q;
#pragma unroll
        for (int k = 0; k < 8; ++k) af[k] = aptr[2 * k];   // af dead after term1 MFMA
#pragma unroll
        for (int i = 0; i < 4; ++i)
            breg[i] = *((const half8*)(xh + (size_t)(bc0 * BT + sr0 + 32 * i) * D) + sg);
        if (tid < BT) {
            int i = br0 * BT + tid;
            int li = labels[i]; int a = anchor[li];
            float sqi = sq[i];
            float e2 = (i == a) ? -1e30f : ap[i] + HALFA - sqi;
            rowE[tid] = make_float4(e2, __int_as_float(li), sqi, 0.f);
        } else if (tid < 2 * BT) {
            int j = bc0 * BT + tid - BT;
            int lj = labels[j]; int a = anchor[lj];
            float sqj = sq[j];
            float e2 = (j == a) ? -1e30f : ap[j] + HALFA - sqj;
            colE[1][tid - BT] = make_float4(e2, __int_as_float(lj), sqj, 0.f);
        }
    }

    // ============ phase 3: term1 hinge epilogue (hides phase-2 latency) ============
    if (hasT1) {
        float4 cj = colE[0][(w & 3) * 32 + m];
        float sqj = cj.x; int labj = __float_as_int(cj.y);
#pragma unroll
        for (int rr = 0; rr < 16; ++rr) {
            int row = (w >> 2) * 32 + (rr & 3) + 8 * (rr >> 2) + 4 * q;
            float Dv = fmaf(-2.f, acc[rr], sSqA[row] + sqj);
            Dv = (labj != c0 + row) ? Dv : DMASK;         // fold label mask into base
            int nf = (sCnt[row] + 3) & ~3;
            cnt += nf;
            for (int gb = 0; gb < nf; gb += 4) {
                float4 ev = *(const float4*)&sge[row * MAXG + gb];
                float u;
                u = ev.x - Dv; local += (__builtin_fabsf(u) < HALFA) ? u : -HALFA;
                u = ev.y - Dv; local += (__builtin_fabsf(u) < HALFA) ? u : -HALFA;
                u = ev.z - Dv; local += (__builtin_fabsf(u) < HALFA) ? u : -HALFA;
                u = ev.w - Dv; local += (__builtin_fabsf(u) < HALFA) ? u : -HALFA;
            }
        }
    }
    __syncthreads();   // rowE/colE[1] ready; Bs free for the walker

    // ============ phase 4: term2 triangle-run walker ============
    {
        const int wr = w >> 1, wc = w & 1;     // 4 row-groups x 2 col-groups
        int cbuf = 1, cur_br = br0;
        int br = br0, bc = br0;
        {   // recompute bc0 (kept out of registers across phases)
            int rem = ts, brx = 0;
            while (rem >= NB - brx) { rem -= NB - brx; ++brx; }
            bc = brx + rem;
        }

        for (int t = ts; t < te; ++t) {
            const int i0 = br * BT;
            const bool diag = (br == bc);

            if (br != cur_br) {                 // row seam: reload A panel + rowE
                cur_br = br;
                const half8* aptr = (const half8*)(xh + (size_t)(i0 + wr * 32 + m) * D) + q;
#pragma unroll
                for (int k8 = 0; k8 < 8; ++k8) af[k8] = aptr[2 * k8];
                if (tid < BT) {
                    int i = i0 + tid;
                    int li = labels[i]; int a = anchor[li];
                    float sqi = sq[i];
                    float e2 = (i == a) ? -1e30f : ap[i] + HALFA - sqi;
                    rowE[tid] = make_float4(e2, __int_as_float(li), sqi, 0.f);
                }
            }

#pragma unroll
            for (int i = 0; i < 4; ++i)
                Bs[sg * SL + sr0 + 32 * i] = breg[i];
            __syncthreads();

            int brn = br, bcn = bc + 1;
            if (bcn == NB) { ++brn; bcn = brn; }
            if (t + 1 < te) {                   // prefetch next tile
                int j0n = bcn * BT;
#pragma unroll
                for (int i = 0; i < 4; ++i)
                    breg[i] = *((const half8*)(xh + (size_t)(j0n + sr0 + 32 * i) * D) + sg);
                if (tid < BT) {
                    int j = j0n + tid;
                    int lj = labels[j]; int a = anchor[lj];
                    float sqj = sq[j];
                    float e2 = (j == a) ? -1e30f : ap[j] + HALFA - sqj;
                    colE[cbuf ^ 1][tid] = make_float4(e2, __int_as_float(lj), sqj, 0.f);
                }
            }

            floatx16 acc0 = zerov(), acc1 = zerov();
#pragma unroll
            for (int k8 = 0; k8 < 8; ++k8) {
                half8 b0 = Bs[(2 * k8 + q) * SL + wc * 64 + m];
                half8 b1 = Bs[(2 * k8 + q) * SL + wc * 64 + 32 + m];
                acc0 = __builtin_amdgcn_mfma_f32_32x32x16_f16(af[k8], b0, acc0, 0, 0, 0);
                acc1 = __builtin_amdgcn_mfma_f32_32x32x16_f16(af[k8], b1, acc1, 0, 0, 0);
            }

            float sqjv[2], e2j[2]; int labj[2];
            { float4 cj = colE[cbuf][wc * 64 + m];      e2j[0] = cj.x; labj[0] = __float_as_int(cj.y); sqjv[0] = cj.z; }
            { float4 cj = colE[cbuf][wc * 64 + 32 + m]; e2j[1] = cj.x; labj[1] = __float_as_int(cj.y); sqjv[1] = cj.z; }

#pragma unroll
            for (int rr = 0; rr < 16; ++rr) {
                int row = wr * 32 + (rr & 3) + 8 * (rr >> 2) + 4 * q;
                float4 re = rowE[row];
                float e2i = re.x, sqi = re.z;
                int labi = __float_as_int(re.y);
#pragma unroll
                for (int tn = 0; tn < 2; ++tn) {
                    float dot = (tn == 0) ? acc0[rr] : acc1[rr];
                    bool ne = (labi != labj[tn]);
                    float b1v = ne ? (e2i - sqjv[tn]) : DMASK;
                    float u2 = fmaf(2.f, dot, b1v);
                    local += (__builtin_fabsf(u2) < HALFA) ? u2 : -HALFA;
                    if (!diag) {
                        float b2v = ne ? (e2j[tn] - sqi) : DMASK;
                        float u2b = fmaf(2.f, dot, b2v);
                        local += (__builtin_fabsf(u2b) < HALFA) ? u2b : -HALFA;
                    }
                }
            }
            cnt += diag ? 32 : 64;
            br = brn; bc = bcn;
            cbuf ^= 1;
            __syncthreads();
        }
    }

    // compensation for the -HALFA branchless accumulation, then block reduce
    local += HALFA * (float)cnt;
#pragma unroll
    for (int off = 32; off; off >>= 1) local += __shfl_down(local, off);
    if (lane == 0) wsum[w] = local;
    __syncthreads();
    if (tid == 0) {
        float s = 0.f;
#pragma unroll
        for (int i = 0; i < 8; ++i) s += wsum[i];
        atomicAdd(out, s);
    }
}

// ---------------- launch ----------------

extern "C" void kernel_launch(void* const* d_in, const int* in_sizes, int n_in,
                              void* d_out, int out_size, void* d_ws, size_t ws_size,
                              hipStream_t stream) {
    const float* x = (const float*)d_in[0];
    const int* labels = (const int*)d_in[1];
    float* out = (float*)d_out;

    char* p = (char*)d_ws;
    int* anchor = (int*)p;        p += C * 4;
    float* sq = (float*)p;        p += N * 4;
    float* ap = (float*)p;        p += N * 4;
    int* ecnt = (int*)p;          p += C * 4;
    float* egrid = (float*)p;     p += (size_t)C * MAXG * 4;
    p = (char*)(((uintptr_t)p + 255) & ~(uintptr_t)255);
    _Float16* xh = (_Float16*)p;  // N*D*2 = 2 MB

    hipMemsetAsync(ecnt, 0, C * 4, stream);   // egrid memset not needed (masked copy)
    k_prep<<<N / 32, 256, 0, stream>>>(x, labels, xh, sq, anchor, ap, ecnt, egrid, out);
    k_main<<<GRID, 512, 0, stream>>>(xh, labels, anchor, sq, ap, ecnt, egrid, out);
}

// Round 11
// 113.670 us; speedup vs baseline: 1.0127x; 1.0127x over previous
//
#include <hip/hip_runtime.h>
#include <limits.h>
#include <stdint.h>

#define ALPHA 0.2f
#define HALFA 0.1f
static constexpr int N = 8192;
static constexpr int D = 128;
static constexpr int C = 512;
static constexpr int BT = 128;                    // tile edge (points per tile)
static constexpr int GR = D / 8;                  // 16 granules (half8) per row
static constexpr int SL = BT + 1;                 // padded row count per granule
static constexpr int MAXG = 48;                   // e-list capacity (mean 16, 8 sigma)
static constexpr int NB = N / BT;                 // 64 row/col panels
static constexpr int NT1T = 512;                  // term1 tiles: 8 class-panels x 64 j-tiles
static constexpr int NTRI = NB * (NB + 1) / 2;    // 2080 term2 triangle tiles
static constexpr int GRID = 768;                  // 3 blocks/CU x 256 CUs (VGPR 60, LDS 52.7K)

// Sentinels: EPAD must differ from DMASK — pad slot with ev==EPAD vs masked base DMASK
// must give |ev-DMASK| >= HALFA (R9 bug: EPAD==DMASK made u=0 -> +HALFA leak per slot).
#define DMASK 3.0e38f
#define EPAD  1.0e37f

using half8    = __attribute__((ext_vector_type(8))) _Float16;
using floatx16 = __attribute__((ext_vector_type(16))) float;

__device__ __forceinline__ floatx16 zerov() { floatx16 v = {0.f}; return v; }

__device__ __forceinline__ half8 cvt8(float4 v0, float4 v1) {
    half8 h;
    h[0] = (_Float16)v0.x; h[1] = (_Float16)v0.y; h[2] = (_Float16)v0.z; h[3] = (_Float16)v0.w;
    h[4] = (_Float16)v1.x; h[5] = (_Float16)v1.y; h[6] = (_Float16)v1.z; h[7] = (_Float16)v1.w;
    return h;
}

__device__ __forceinline__ float ss8(float4 v0, float4 v1) {
    return v0.x*v0.x + v0.y*v0.y + v0.z*v0.z + v0.w*v0.w
         + v1.x*v1.x + v1.y*v1.y + v1.z*v1.z + v1.w*v1.w;
}

// ---- k_prep: anchors + xh (fp16) + sq + ap + GLOBAL e-lists ---------------------------
// (pads of egrid are NOT initialized; k_main masks them via ecnt during the LDS copy)

__launch_bounds__(256)
__global__ void k_prep(const float* __restrict__ x, const int* __restrict__ labels,
                       _Float16* __restrict__ xh, float* __restrict__ sq,
                       int* __restrict__ anchorg, float* __restrict__ ap,
                       int* __restrict__ ecnt, float* __restrict__ egrid,
                       float* __restrict__ out) {
    __shared__ int sAnc[C];
    const int tid = threadIdx.x;
    if (blockIdx.x == 0 && tid == 0) out[0] = 0.f;
    for (int i = tid; i < C; i += 256) sAnc[i] = INT_MAX;
    __syncthreads();
    const int4* lab4 = (const int4*)labels;
    for (int t = tid; t < N / 4; t += 256) {
        int4 lv = lab4[t];
        int base = 4 * t;
        atomicMin(&sAnc[lv.x], base);
        atomicMin(&sAnc[lv.y], base + 1);
        atomicMin(&sAnc[lv.z], base + 2);
        atomicMin(&sAnc[lv.w], base + 3);
    }
    __syncthreads();
    if (tid < 2) {
        int c = blockIdx.x * 2 + tid;
        int a = sAnc[c];
        anchorg[c] = (a == INT_MAX) ? -1 : a;
    }

    const int r = blockIdx.x * 32 + (tid >> 3);
    const int sub = tid & 7;
    const float4* src = (const float4*)(x + (size_t)r * D) + sub * 4;
    half8* dst = (half8*)(xh + (size_t)r * D) + sub * 2;
    half8 hj[2];
    float ssj = 0.f;
#pragma unroll
    for (int i = 0; i < 2; ++i) {
        float4 v0 = src[2 * i], v1 = src[2 * i + 1];
        hj[i] = cvt8(v0, v1);
        dst[i] = hj[i];
        ssj += ss8(v0, v1);
    }
    ssj += __shfl_xor(ssj, 1); ssj += __shfl_xor(ssj, 2); ssj += __shfl_xor(ssj, 4);

    const int lab = labels[r];
    const int a = sAnc[lab];
    const float4* asrc = (const float4*)(x + (size_t)a * D) + sub * 4;
    float ssa = 0.f, dot = 0.f;
#pragma unroll
    for (int i = 0; i < 2; ++i) {
        float4 a0 = asrc[2 * i], a1 = asrc[2 * i + 1];
        half8 ha = cvt8(a0, a1);
        ssa += ss8(a0, a1);
#pragma unroll
        for (int e = 0; e < 8; ++e) dot = fmaf((float)ha[e], (float)hj[i][e], dot);
    }
    ssa += __shfl_xor(ssa, 1); ssa += __shfl_xor(ssa, 2); ssa += __shfl_xor(ssa, 4);
    dot += __shfl_xor(dot, 1); dot += __shfl_xor(dot, 2); dot += __shfl_xor(dot, 4);
    if (sub == 0) {
        float apv = ssa + ssj - 2.f * dot;
        sq[r] = ssj;
        ap[r] = apv;
        if (r != a) {   // append to the class e-list (anchor itself excluded)
            int slot = atomicAdd(&ecnt[lab], 1);
            if (slot < MAXG) egrid[(size_t)lab * MAXG + slot] = apv + HALFA;
        }
    }
}

// ---- k_main: 768 blocks, 3/CU, MEASURED-ratio balanced split --------------------------
// Cost model (R10 post-mortem): term1 tile ~= 4 term2 tiles (140K vs 33K hinges).
// Balance 4 + x/512 = (2080-x)/256 -> x = 672 term2 tiles ride with term1 blocks:
//   b <160:        term1 + t2 [2b, 2b+2)            (6u)
//   b in[160,512): term1 + t2 [320+(b-160), +1)     (5u)
//   b in[512,640): t2 [672+6(b-512), +6)            (6u)
//   b in[640,768): t2 [1440+5(b-640), +5)           (5u)
// Inner loops byte-identical to R8/R10. __launch_bounds__(512,2): proven no-spill.

__launch_bounds__(512, 2)
__global__ void k_main(const _Float16* __restrict__ xh, const int* __restrict__ labels,
                       const int* __restrict__ anchor, const float* __restrict__ sq,
                       const float* __restrict__ ap, const int* __restrict__ ecnt,
                       const float* __restrict__ egrid, float* __restrict__ out) {
    __shared__ __align__(16) _Float16 BsH[GR * SL * 8];   // 33024 B, K-major [granule][row]
    __shared__ __align__(16) float sge[64 * MAXG];        // 12288 B e-lists
    __shared__ float4 rowE[BT];
    __shared__ float4 colE[2][BT];
    __shared__ int   sArow[64];
    __shared__ float sSqA[64];
    __shared__ int   sCnt[64];
    __shared__ float wsum[8];
    half8* Bs = (half8*)BsH;

    const int tid = threadIdx.x;
    const int lane = tid & 63, w = tid >> 6;
    const int m = lane & 31, q = lane >> 5;
    const int sg = tid & 15, sr0 = tid >> 4;   // staging: granule, row base
    float local = 0.f;
    int cnt = 0;                                // hinge slots evaluated (for +h*cnt)

    const int b = blockIdx.x;
    const bool hasT1 = (b < NT1T);
    // term1 tile coords
    const int c0 = (b >> 6) * 64, j1 = (b & 63) * BT;
    // term2 run [ts, te) — measured-ratio balanced split
    int ts, te;
    if (b < 160)      { ts = 2 * b;                te = ts + 2; }
    else if (b < 512) { ts = 320 + (b - 160);      te = ts + 1; }
    else if (b < 640) { ts = 672 + 6 * (b - 512);  te = ts + 6; }
    else              { ts = 1440 + 5 * (b - 640); te = ts + 5; }

    half8 af[8], breg[4];
    floatx16 acc = zerov();

    if (hasT1) {
        // ============ phase 0: term1 meta + masked e-list copy + B/colE prefetch ============
        if (tid < 64) {
            int c = c0 + tid;
            int a = anchor[c];
            int ar = (a < 0) ? 0 : a;          // dummy (absent class has cnt 0)
            sArow[tid] = ar;
            sSqA[tid] = sq[ar];
            int n = ecnt[c];
            sCnt[tid] = (n > MAXG) ? MAXG : n;
        }
        {   // e-list copy with pad masking (egrid pads are uninitialized) -> EPAD
            const float4* srcv = (const float4*)(egrid + (size_t)c0 * MAXG);
            float4* dstv = (float4*)sge;
#pragma unroll
            for (int rep = 0; rep < 2; ++rep) {
                int idx = tid + rep * 512;
                if (idx < 64 * (MAXG / 4)) {
                    int cls = idx / (MAXG / 4);
                    int sb = (idx % (MAXG / 4)) * 4;
                    int n = ecnt[c0 + cls]; n = (n > MAXG) ? MAXG : n;
                    float4 v = srcv[idx];
                    v.x = (sb + 0 < n) ? v.x : EPAD;
                    v.y = (sb + 1 < n) ? v.y : EPAD;
                    v.z = (sb + 2 < n) ? v.z : EPAD;
                    v.w = (sb + 3 < n) ? v.w : EPAD;
                    dstv[idx] = v;
                }
            }
        }
#pragma unroll
        for (int i = 0; i < 4; ++i)
            breg[i] = *((const half8*)(xh + (size_t)(j1 + sr0 + 32 * i) * D) + sg);
        if (tid < BT) {
            int j = j1 + tid;
            colE[0][tid] = make_float4(sq[j], __int_as_float(labels[j]), 0.f, 0.f);
        }
        __syncthreads();

        // ============ phase 1: term1 MFMA ============
        {   // gathered anchor rows; 2 row-groups x 4 col-groups
            int arow = sArow[(w >> 2) * 32 + m];
            const half8* aptr = (const half8*)(xh + (size_t)arow * D) + q;
#pragma unroll
            for (int k = 0; k < 8; ++k) af[k] = aptr[2 * k];
        }
#pragma unroll
        for (int i = 0; i < 4; ++i)
            Bs[sg * SL + sr0 + 32 * i] = breg[i];
        __syncthreads();

#pragma unroll
        for (int k = 0; k < 8; ++k) {
            half8 b0 = Bs[(2 * k + q) * SL + (w & 3) * 32 + m];
            acc = __builtin_amdgcn_mfma_f32_32x32x16_f16(af[k], b0, acc, 0, 0, 0);
        }
    }

    // ============ phase 2: prefetch first term2 tile (all blocks) ============
    int br0 = 0;
    {
        int rem = ts;
        while (rem >= NB - br0) { rem -= NB - br0; ++br0; }
        int bc0 = br0 + rem;
        const half8* aptr = (const half8*)(xh + (size_t)(br0 * BT + (w >> 1) * 32 + m) * D) + q;
#pragma unroll
        for (int k = 0; k < 8; ++k) af[k] = aptr[2 * k];   // af dead after term1 MFMA
#pragma unroll
        for (int i = 0; i < 4; ++i)
            breg[i] = *((const half8*)(xh + (size_t)(bc0 * BT + sr0 + 32 * i) * D) + sg);
        if (tid < BT) {
            int i = br0 * BT + tid;
            int li = labels[i]; int a = anchor[li];
            float sqi = sq[i];
            float e2 = (i == a) ? -1e30f : ap[i] + HALFA - sqi;
            rowE[tid] = make_float4(e2, __int_as_float(li), sqi, 0.f);
        } else if (tid < 2 * BT) {
            int j = bc0 * BT + tid - BT;
            int lj = labels[j]; int a = anchor[lj];
            float sqj = sq[j];
            float e2 = (j == a) ? -1e30f : ap[j] + HALFA - sqj;
            colE[1][tid - BT] = make_float4(e2, __int_as_float(lj), sqj, 0.f);
        }
    }

    // ============ phase 3: term1 hinge epilogue (hides phase-2 latency) ============
    if (hasT1) {
        float4 cj = colE[0][(w & 3) * 32 + m];
        float sqj = cj.x; int labj = __float_as_int(cj.y);
#pragma unroll
        for (int rr = 0; rr < 16; ++rr) {
            int row = (w >> 2) * 32 + (rr & 3) + 8 * (rr >> 2) + 4 * q;
            float Dv = fmaf(-2.f, acc[rr], sSqA[row] + sqj);
            Dv = (labj != c0 + row) ? Dv : DMASK;         // fold label mask into base
            int nf = (sCnt[row] + 3) & ~3;
            cnt += nf;
            for (int gb = 0; gb < nf; gb += 4) {
                float4 ev = *(const float4*)&sge[row * MAXG + gb];
                float u;
                u = ev.x - Dv; local += (__builtin_fabsf(u) < HALFA) ? u : -HALFA;
                u = ev.y - Dv; local += (__builtin_fabsf(u) < HALFA) ? u : -HALFA;
                u = ev.z - Dv; local += (__builtin_fabsf(u) < HALFA) ? u : -HALFA;
                u = ev.w - Dv; local += (__builtin_fabsf(u) < HALFA) ? u : -HALFA;
            }
        }
    }
    __syncthreads();   // rowE/colE[1] ready; Bs free for the walker

    // ============ phase 4: term2 triangle-run walker ============
    {
        const int wr = w >> 1, wc = w & 1;     // 4 row-groups x 2 col-groups
        int cbuf = 1, cur_br = br0;
        int br = br0, bc = br0;
        {   // recompute bc0 (kept out of registers across phases)
            int rem = ts, brx = 0;
            while (rem >= NB - brx) { rem -= NB - brx; ++brx; }
            bc = brx + rem;
        }

        for (int t = ts; t < te; ++t) {
            const int i0 = br * BT;
            const bool diag = (br == bc);

            if (br != cur_br) {                 // row seam: reload A panel + rowE
                cur_br = br;
                const half8* aptr = (const half8*)(xh + (size_t)(i0 + wr * 32 + m) * D) + q;
#pragma unroll
                for (int k8 = 0; k8 < 8; ++k8) af[k8] = aptr[2 * k8];
                if (tid < BT) {
                    int i = i0 + tid;
                    int li = labels[i]; int a = anchor[li];
                    float sqi = sq[i];
                    float e2 = (i == a) ? -1e30f : ap[i] + HALFA - sqi;
                    rowE[tid] = make_float4(e2, __int_as_float(li), sqi, 0.f);
                }
            }

#pragma unroll
            for (int i = 0; i < 4; ++i)
                Bs[sg * SL + sr0 + 32 * i] = breg[i];
            __syncthreads();

            int brn = br, bcn = bc + 1;
            if (bcn == NB) { ++brn; bcn = brn; }
            if (t + 1 < te) {                   // prefetch next tile
                int j0n = bcn * BT;
#pragma unroll
                for (int i = 0; i < 4; ++i)
                    breg[i] = *((const half8*)(xh + (size_t)(j0n + sr0 + 32 * i) * D) + sg);
                if (tid < BT) {
                    int j = j0n + tid;
                    int lj = labels[j]; int a = anchor[lj];
                    float sqj = sq[j];
                    float e2 = (j == a) ? -1e30f : ap[j] + HALFA - sqj;
                    colE[cbuf ^ 1][tid] = make_float4(e2, __int_as_float(lj), sqj, 0.f);
                }
            }

            floatx16 acc0 = zerov(), acc1 = zerov();
#pragma unroll
            for (int k8 = 0; k8 < 8; ++k8) {
                half8 b0 = Bs[(2 * k8 + q) * SL + wc * 64 + m];
                half8 b1 = Bs[(2 * k8 + q) * SL + wc * 64 + 32 + m];
                acc0 = __builtin_amdgcn_mfma_f32_32x32x16_f16(af[k8], b0, acc0, 0, 0, 0);
                acc1 = __builtin_amdgcn_mfma_f32_32x32x16_f16(af[k8], b1, acc1, 0, 0, 0);
            }

            float sqjv[2], e2j[2]; int labj[2];
            { float4 cj = colE[cbuf][wc * 64 + m];      e2j[0] = cj.x; labj[0] = __float_as_int(cj.y); sqjv[0] = cj.z; }
            { float4 cj = colE[cbuf][wc * 64 + 32 + m]; e2j[1] = cj.x; labj[1] = __float_as_int(cj.y); sqjv[1] = cj.z; }

#pragma unroll
            for (int rr = 0; rr < 16; ++rr) {
                int row = wr * 32 + (rr & 3) + 8 * (rr >> 2) + 4 * q;
                float4 re = rowE[row];
                float e2i = re.x, sqi = re.z;
                int labi = __float_as_int(re.y);
#pragma unroll
                for (int tn = 0; tn < 2; ++tn) {
                    float dot = (tn == 0) ? acc0[rr] : acc1[rr];
                    bool ne = (labi != labj[tn]);
                    float b1v = ne ? (e2i - sqjv[tn]) : DMASK;
                    float u2 = fmaf(2.f, dot, b1v);
                    local += (__builtin_fabsf(u2) < HALFA) ? u2 : -HALFA;
                    if (!diag) {
                        float b2v = ne ? (e2j[tn] - sqi) : DMASK;
                        float u2b = fmaf(2.f, dot, b2v);
                        local += (__builtin_fabsf(u2b) < HALFA) ? u2b : -HALFA;
                    }
                }
            }
            cnt += diag ? 32 : 64;
            br = brn; bc = bcn;
            cbuf ^= 1;
            __syncthreads();
        }
    }

    // compensation for the -HALFA branchless accumulation, then block reduce
    local += HALFA * (float)cnt;
#pragma unroll
    for (int off = 32; off; off >>= 1) local += __shfl_down(local, off);
    if (lane == 0) wsum[w] = local;
    __syncthreads();
    if (tid == 0) {
        float s = 0.f;
#pragma unroll
        for (int i = 0; i < 8; ++i) s += wsum[i];
        atomicAdd(out, s);
    }
}

// ---------------- launch ----------------

extern "C" void kernel_launch(void* const* d_in, const int* in_sizes, int n_in,
                              void* d_out, int out_size, void* d_ws, size_t ws_size,
                              hipStream_t stream) {
    const float* x = (const float*)d_in[0];
    const int* labels = (const int*)d_in[1];
    float* out = (float*)d_out;

    char* p = (char*)d_ws;
    int* anchor = (int*)p;        p += C * 4;
    float* sq = (float*)p;        p += N * 4;
    float* ap = (float*)p;        p += N * 4;
    int* ecnt = (int*)p;          p += C * 4;
    float* egrid = (float*)p;     p += (size_t)C * MAXG * 4;
    p = (char*)(((uintptr_t)p + 255) & ~(uintptr_t)255);
    _Float16* xh = (_Float16*)p;  // N*D*2 = 2 MB

    hipMemsetAsync(ecnt, 0, C * 4, stream);   // egrid memset not needed (masked copy)
    k_prep<<<N / 32, 256, 0, stream>>>(x, labels, xh, sq, anchor, ap, ecnt, egrid, out);
    k_main<<<GRID, 512, 0, stream>>>(xh, labels, anchor, sq, ap, ecnt, egrid, out);
}

// Round 12
// 105.109 us; speedup vs baseline: 1.0952x; 1.0814x over previous
//
#include <hip/hip_runtime.h>
#include <limits.h>
#include <stdint.h>

#define ALPHA 0.2f
#define HALFA 0.1f
static constexpr int N = 8192;
static constexpr int D = 128;
static constexpr int C = 512;
static constexpr int BT = 128;                    // tile edge (points per tile)
static constexpr int GR = D / 8;                  // 16 granules (half8) per row
static constexpr int SL = BT + 1;                 // padded row count per granule
static constexpr int MAXG = 48;                   // e-list capacity (mean 16, 8 sigma)
static constexpr int NB = N / BT;                 // 64 row/col panels
static constexpr int NT1T = 512;                  // term1 tiles: 8 class-panels x 64 j-tiles
static constexpr int NSP = NB / 2;                // 32 superpanels (panel k + panel 63-k)
static constexpr int SPB = 16;                    // walker lanes per superpanel
static constexpr int GRID = 512;                  // R8-proven: 2/CU, every block identical mix

// Sentinels: EPAD must differ from DMASK (R9 lesson): |EPAD-DMASK| and |EPAD-anyDv|
// must be >= HALFA so pad slots never enter the band.
#define DMASK 3.0e38f
#define EPAD  1.0e37f

using half8    = __attribute__((ext_vector_type(8))) _Float16;
using floatx16 = __attribute__((ext_vector_type(16))) float;

__device__ __forceinline__ floatx16 zerov() { floatx16 v = {0.f}; return v; }

__device__ __forceinline__ half8 cvt8(float4 v0, float4 v1) {
    half8 h;
    h[0] = (_Float16)v0.x; h[1] = (_Float16)v0.y; h[2] = (_Float16)v0.z; h[3] = (_Float16)v0.w;
    h[4] = (_Float16)v1.x; h[5] = (_Float16)v1.y; h[6] = (_Float16)v1.z; h[7] = (_Float16)v1.w;
    return h;
}

__device__ __forceinline__ float ss8(float4 v0, float4 v1) {
    return v0.x*v0.x + v0.y*v0.y + v0.z*v0.z + v0.w*v0.w
         + v1.x*v1.x + v1.y*v1.y + v1.z*v1.z + v1.w*v1.w;
}

// superpanel k: tiles 0..lenA-1 are (br=k, bc=k+t); rest are (br=63-k, bc=63-k+t-lenA)
__device__ __forceinline__ void dec_sp(int k, int t, int lenA, int& br, int& bc) {
    if (t < lenA) { br = k;      bc = k + t; }
    else          { br = 63 - k; bc = 63 - k + (t - lenA); }
}

// ---- k_prep: anchors + xh (fp16) + sq + ap + GLOBAL e-lists ---------------------------
// (egrid pads are NOT initialized; k_main masks them via ecnt during the LDS copy)

__launch_bounds__(256)
__global__ void k_prep(const float* __restrict__ x, const int* __restrict__ labels,
                       _Float16* __restrict__ xh, float* __restrict__ sq,
                       int* __restrict__ anchorg, float* __restrict__ ap,
                       int* __restrict__ ecnt, float* __restrict__ egrid,
                       float* __restrict__ out) {
    __shared__ int sAnc[C];
    const int tid = threadIdx.x;
    if (blockIdx.x == 0 && tid == 0) out[0] = 0.f;
    for (int i = tid; i < C; i += 256) sAnc[i] = INT_MAX;
    __syncthreads();
    const int4* lab4 = (const int4*)labels;
    for (int t = tid; t < N / 4; t += 256) {
        int4 lv = lab4[t];
        int base = 4 * t;
        atomicMin(&sAnc[lv.x], base);
        atomicMin(&sAnc[lv.y], base + 1);
        atomicMin(&sAnc[lv.z], base + 2);
        atomicMin(&sAnc[lv.w], base + 3);
    }
    __syncthreads();
    if (tid < 2) {
        int c = blockIdx.x * 2 + tid;
        int a = sAnc[c];
        anchorg[c] = (a == INT_MAX) ? -1 : a;
    }

    const int r = blockIdx.x * 32 + (tid >> 3);
    const int sub = tid & 7;
    const float4* src = (const float4*)(x + (size_t)r * D) + sub * 4;
    half8* dst = (half8*)(xh + (size_t)r * D) + sub * 2;
    half8 hj[2];
    float ssj = 0.f;
#pragma unroll
    for (int i = 0; i < 2; ++i) {
        float4 v0 = src[2 * i], v1 = src[2 * i + 1];
        hj[i] = cvt8(v0, v1);
        dst[i] = hj[i];
        ssj += ss8(v0, v1);
    }
    ssj += __shfl_xor(ssj, 1); ssj += __shfl_xor(ssj, 2); ssj += __shfl_xor(ssj, 4);

    const int lab = labels[r];
    const int a = sAnc[lab];
    const float4* asrc = (const float4*)(x + (size_t)a * D) + sub * 4;
    float ssa = 0.f, dot = 0.f;
#pragma unroll
    for (int i = 0; i < 2; ++i) {
        float4 a0 = asrc[2 * i], a1 = asrc[2 * i + 1];
        half8 ha = cvt8(a0, a1);
        ssa += ss8(a0, a1);
#pragma unroll
        for (int e = 0; e < 8; ++e) dot = fmaf((float)ha[e], (float)hj[i][e], dot);
    }
    ssa += __shfl_xor(ssa, 1); ssa += __shfl_xor(ssa, 2); ssa += __shfl_xor(ssa, 4);
    dot += __shfl_xor(dot, 1); dot += __shfl_xor(dot, 2); dot += __shfl_xor(dot, 4);
    if (sub == 0) {
        float apv = ssa + ssj - 2.f * dot;
        sq[r] = ssj;
        ap[r] = apv;
        if (r != a) {   // append to the class e-list (anchor itself excluded)
            int slot = atomicAdd(&ecnt[lab], 1);
            if (slot < MAXG) egrid[(size_t)lab * MAXG + slot] = apv + HALFA;
        }
    }
}

// ---- k_main: R8-proven schedule — 512 identical blocks (2/CU), each 1 term1 tile then
// a superpanel walker lane (4-5 term2 tiles). Deltas vs R8: (a) EPAD-masked e-list copy
// (drops egrid memset), (b) term2 hinge folds ne-mask into the band compare (s_and on
// SALU instead of a VALU cndmask on the base), (c) s_setprio around VALU-hot epilogues.
// __launch_bounds__(512,2): proven no-spill; do NOT tighten (R4/R6 spill disasters).

__launch_bounds__(512, 2)
__global__ void k_main(const _Float16* __restrict__ xh, const int* __restrict__ labels,
                       const int* __restrict__ anchor, const float* __restrict__ sq,
                       const float* __restrict__ ap, const int* __restrict__ ecnt,
                       const float* __restrict__ egrid, float* __restrict__ out) {
    __shared__ __align__(16) _Float16 BsH[GR * SL * 8];   // 33024 B, K-major [granule][row]
    __shared__ __align__(16) float sge[64 * MAXG];        // 12288 B e-lists
    __shared__ float4 rowE[BT];
    __shared__ float4 colE[2][BT];
    __shared__ int   sArow[64];
    __shared__ float sSqA[64];
    __shared__ int   sCnt[64];
    __shared__ float wsum[8];
    half8* Bs = (half8*)BsH;

    const int tid = threadIdx.x;
    const int lane = tid & 63, w = tid >> 6;
    const int m = lane & 31, q = lane >> 5;
    const int sg = tid & 15, sr0 = tid >> 4;   // staging: granule, row base
    float local = 0.f;
    int cnt = 0;                                // hinge slots evaluated (for +h*cnt)

    const int b = blockIdx.x;
    // term1 tile coords (one tile per block: 8 class-panels x 64 j-tiles)
    const int c0 = (b >> 6) * 64, j1 = (b & 63) * BT;
    // term2 walker coords (superpanel k, lane p)
    const int kk_sp = b >> 4, p = b & 15;
    const int lenA = 64 - kk_sp;

    half8 af[8], breg[4];
    floatx16 acc = zerov();

    // ================= phase 0: term1 meta + EPAD-masked e-list copy + B prefetch =======
    if (tid < 64) {
        int c = c0 + tid;
        int a = anchor[c];
        int ar = (a < 0) ? 0 : a;          // dummy (absent class has cnt 0)
        sArow[tid] = ar;
        sSqA[tid] = sq[ar];
        int n = ecnt[c];
        sCnt[tid] = (n > MAXG) ? MAXG : n;
    }
    {   // e-list copy; pads (uninitialized in egrid) forced to EPAD
        const float4* srcv = (const float4*)(egrid + (size_t)c0 * MAXG);
        float4* dstv = (float4*)sge;
#pragma unroll
        for (int rep = 0; rep < 2; ++rep) {
            int idx = tid + rep * 512;
            if (idx < 64 * (MAXG / 4)) {
                int cls = idx / (MAXG / 4);
                int sb = (idx % (MAXG / 4)) * 4;
                int n = ecnt[c0 + cls]; n = (n > MAXG) ? MAXG : n;
                float4 v = srcv[idx];
                v.x = (sb + 0 < n) ? v.x : EPAD;
                v.y = (sb + 1 < n) ? v.y : EPAD;
                v.z = (sb + 2 < n) ? v.z : EPAD;
                v.w = (sb + 3 < n) ? v.w : EPAD;
                dstv[idx] = v;
            }
        }
    }
#pragma unroll
    for (int i = 0; i < 4; ++i)
        breg[i] = *((const half8*)(xh + (size_t)(j1 + sr0 + 32 * i) * D) + sg);
    if (tid < BT) {
        int j = j1 + tid;
        colE[0][tid] = make_float4(sq[j], __int_as_float(labels[j]), 0.f, 0.f);
    }
    __syncthreads();

    // ================= phase 1: term1 MFMA =================
    {   // gathered anchor rows; 2 row-groups x 4 col-groups
        int arow = sArow[(w >> 2) * 32 + m];
        const half8* aptr = (const half8*)(xh + (size_t)arow * D) + q;
#pragma unroll
        for (int k = 0; k < 8; ++k) af[k] = aptr[2 * k];
    }
#pragma unroll
    for (int i = 0; i < 4; ++i)
        Bs[sg * SL + sr0 + 32 * i] = breg[i];
    __syncthreads();

#pragma unroll
    for (int k = 0; k < 8; ++k) {
        half8 b0 = Bs[(2 * k + q) * SL + (w & 3) * 32 + m];
        acc = __builtin_amdgcn_mfma_f32_32x32x16_f16(af[k], b0, acc, 0, 0, 0);
    }

    // ================= phase 2: prefetch first term2 tile (hides under epilogue) =======
    int br0, bc0;
    dec_sp(kk_sp, p, lenA, br0, bc0);
    {
        const half8* aptr = (const half8*)(xh + (size_t)(br0 * BT + (w >> 1) * 32 + m) * D) + q;
#pragma unroll
        for (int k = 0; k < 8; ++k) af[k] = aptr[2 * k];   // af dead after term1 MFMA
#pragma unroll
        for (int i = 0; i < 4; ++i)
            breg[i] = *((const half8*)(xh + (size_t)(bc0 * BT + sr0 + 32 * i) * D) + sg);
        if (tid < BT) {
            int i = br0 * BT + tid;
            int li = labels[i]; int a = anchor[li];
            float sqi = sq[i];
            float e2 = (i == a) ? -1e30f : ap[i] + HALFA - sqi;
            rowE[tid] = make_float4(e2, __int_as_float(li), sqi, 0.f);
        } else if (tid < 2 * BT) {
            int j = bc0 * BT + tid - BT;
            int lj = labels[j]; int a = anchor[lj];
            float sqj = sq[j];
            float e2 = (j == a) ? -1e30f : ap[j] + HALFA - sqj;
            colE[1][tid - BT] = make_float4(e2, __int_as_float(lj), sqj, 0.f);
        }
    }

    // ================= phase 3: term1 hinge epilogue =================
    __builtin_amdgcn_s_setprio(1);
    {
        float4 cj = colE[0][(w & 3) * 32 + m];
        float sqj = cj.x; int labj = __float_as_int(cj.y);
#pragma unroll
        for (int rr = 0; rr < 16; ++rr) {
            int row = (w >> 2) * 32 + (rr & 3) + 8 * (rr >> 2) + 4 * q;
            float Dv = fmaf(-2.f, acc[rr], sSqA[row] + sqj);
            Dv = (labj != c0 + row) ? Dv : DMASK;         // fold label mask into base
            int nf = (sCnt[row] + 3) & ~3;
            cnt += nf;
            for (int gb = 0; gb < nf; gb += 4) {
                float4 ev = *(const float4*)&sge[row * MAXG + gb];
                float u;
                u = ev.x - Dv; local += (__builtin_fabsf(u) < HALFA) ? u : -HALFA;
                u = ev.y - Dv; local += (__builtin_fabsf(u) < HALFA) ? u : -HALFA;
                u = ev.z - Dv; local += (__builtin_fabsf(u) < HALFA) ? u : -HALFA;
                u = ev.w - Dv; local += (__builtin_fabsf(u) < HALFA) ? u : -HALFA;
            }
        }
    }
    __builtin_amdgcn_s_setprio(0);
    __syncthreads();   // rowE/colE[1] ready; Bs free for the walker

    // ================= phase 4: term2 superpanel walker =================
    {
        const int wr = w >> 1, wc = w & 1;     // 4 row-groups x 2 col-groups
        int cbuf = 1, cur_br = br0;

        for (int t = p; t < 65; t += SPB) {
            int br, bc; dec_sp(kk_sp, t, lenA, br, bc);
            const int i0 = br * BT;
            const bool diag = (br == bc);

            if (br != cur_br) {                 // at most one seam per block
                cur_br = br;
                const half8* aptr = (const half8*)(xh + (size_t)(i0 + wr * 32 + m) * D) + q;
#pragma unroll
                for (int k8 = 0; k8 < 8; ++k8) af[k8] = aptr[2 * k8];
                if (tid < BT) {
                    int i = i0 + tid;
                    int li = labels[i]; int a = anchor[li];
                    float sqi = sq[i];
                    float e2 = (i == a) ? -1e30f : ap[i] + HALFA - sqi;
                    rowE[tid] = make_float4(e2, __int_as_float(li), sqi, 0.f);
                }
            }

#pragma unroll
            for (int i = 0; i < 4; ++i)
                Bs[sg * SL + sr0 + 32 * i] = breg[i];
            __syncthreads();

            if (t + SPB < 65) {                 // prefetch next tile
                int brn, bcn; dec_sp(kk_sp, t + SPB, lenA, brn, bcn);
                int j0n = bcn * BT;
#pragma unroll
                for (int i = 0; i < 4; ++i)
                    breg[i] = *((const half8*)(xh + (size_t)(j0n + sr0 + 32 * i) * D) + sg);
                if (tid < BT) {
                    int j = j0n + tid;
                    int lj = labels[j]; int a = anchor[lj];
                    float sqj = sq[j];
                    float e2 = (j == a) ? -1e30f : ap[j] + HALFA - sqj;
                    colE[cbuf ^ 1][tid] = make_float4(e2, __int_as_float(lj), sqj, 0.f);
                }
            }

            __builtin_amdgcn_s_setprio(1);
            floatx16 acc0 = zerov(), acc1 = zerov();
#pragma unroll
            for (int k8 = 0; k8 < 8; ++k8) {
                half8 b0 = Bs[(2 * k8 + q) * SL + wc * 64 + m];
                half8 b1 = Bs[(2 * k8 + q) * SL + wc * 64 + 32 + m];
                acc0 = __builtin_amdgcn_mfma_f32_32x32x16_f16(af[k8], b0, acc0, 0, 0, 0);
                acc1 = __builtin_amdgcn_mfma_f32_32x32x16_f16(af[k8], b1, acc1, 0, 0, 0);
            }

            float sqjv[2], e2j[2]; int labj[2];
            { float4 cj = colE[cbuf][wc * 64 + m];      e2j[0] = cj.x; labj[0] = __float_as_int(cj.y); sqjv[0] = cj.z; }
            { float4 cj = colE[cbuf][wc * 64 + 32 + m]; e2j[1] = cj.x; labj[1] = __float_as_int(cj.y); sqjv[1] = cj.z; }

#pragma unroll
            for (int rr = 0; rr < 16; ++rr) {
                int row = wr * 32 + (rr & 3) + 8 * (rr >> 2) + 4 * q;
                float4 re = rowE[row];
                float e2i = re.x, sqi = re.z;
                int labi = __float_as_int(re.y);
#pragma unroll
                for (int tn = 0; tn < 2; ++tn) {
                    float dot = (tn == 0) ? acc0[rr] : acc1[rr];
                    // ne-mask folded into the band predicate: v_cmp + v_cmp + s_and (SALU)
                    // instead of cndmask-ing the base to DMASK (saves 1 VALU/hinge; ne shared
                    // between both orientations).
                    bool ne = (labi != labj[tn]);
                    float u2 = fmaf(2.f, dot, e2i - sqjv[tn]);
                    local += (ne & (__builtin_fabsf(u2) < HALFA)) ? u2 : -HALFA;
                    if (!diag) {
                        float u2b = fmaf(2.f, dot, e2j[tn] - sqi);
                        local += (ne & (__builtin_fabsf(u2b) < HALFA)) ? u2b : -HALFA;
                    }
                }
            }
            __builtin_amdgcn_s_setprio(0);
            cnt += diag ? 32 : 64;
            cbuf ^= 1;
            __syncthreads();
        }
    }

    // compensation for the -HALFA branchless accumulation, then block reduce
    local += HALFA * (float)cnt;
#pragma unroll
    for (int off = 32; off; off >>= 1) local += __shfl_down(local, off);
    if (lane == 0) wsum[w] = local;
    __syncthreads();
    if (tid == 0) {
        float s = 0.f;
#pragma unroll
        for (int i = 0; i < 8; ++i) s += wsum[i];
        atomicAdd(out, s);
    }
}

// ---------------- launch ----------------

extern "C" void kernel_launch(void* const* d_in, const int* in_sizes, int n_in,
                              void* d_out, int out_size, void* d_ws, size_t ws_size,
                              hipStream_t stream) {
    const float* x = (const float*)d_in[0];
    const int* labels = (const int*)d_in[1];
    float* out = (float*)d_out;

    char* p = (char*)d_ws;
    int* anchor = (int*)p;        p += C * 4;
    float* sq = (float*)p;        p += N * 4;
    float* ap = (float*)p;        p += N * 4;
    int* ecnt = (int*)p;          p += C * 4;
    float* egrid = (float*)p;     p += (size_t)C * MAXG * 4;
    p = (char*)(((uintptr_t)p + 255) & ~(uintptr_t)255);
    _Float16* xh = (_Float16*)p;  // N*D*2 = 2 MB

    hipMemsetAsync(ecnt, 0, C * 4, stream);   // egrid memset not needed (masked copy)
    k_prep<<<N / 32, 256, 0, stream>>>(x, labels, xh, sq, anchor, ap, ecnt, egrid, out);
    k_main<<<GRID, 512, 0, stream>>>(xh, labels, anchor, sq, ap, ecnt, egrid, out);
}

// Round 14
// 104.582 us; speedup vs baseline: 1.1007x; 1.0050x over previous
//
#include <hip/hip_runtime.h>
#include <limits.h>
#include <stdint.h>

#define ALPHA 0.2f
#define HALFA 0.1f
static constexpr int N = 8192;
static constexpr int D = 128;
static constexpr int C = 512;
static constexpr int BT = 128;                    // tile edge (points per tile)
static constexpr int GR = D / 8;                  // 16 granules (half8) per row
static constexpr int SL = BT + 1;                 // padded row count per granule
static constexpr int MAXG = 48;                   // e-list capacity (mean 16, 8 sigma; 8-divisible)
static constexpr int NB = N / BT;                 // 64 row/col panels
static constexpr int NSP = NB / 2;                // 32 superpanels (panel k + panel 63-k)
static constexpr int SPB = 16;                    // walker lanes per superpanel
static constexpr int GRID = 512;                  // R8/R12-proven: 2/CU, identical block mix

// Sentinels: EPAD must differ from DMASK (R9 lesson): |EPAD-DMASK| >= HALFA so pad
// slots never enter the band, under normal Dv or DMASK'd Dv.
#define DMASK 3.0e38f
#define EPAD  1.0e37f

using half8    = __attribute__((ext_vector_type(8))) _Float16;
using floatx16 = __attribute__((ext_vector_type(16))) float;

__device__ __forceinline__ floatx16 zerov() { floatx16 v = {0.f}; return v; }

__device__ __forceinline__ half8 cvt8(float4 v0, float4 v1) {
    half8 h;
    h[0] = (_Float16)v0.x; h[1] = (_Float16)v0.y; h[2] = (_Float16)v0.z; h[3] = (_Float16)v0.w;
    h[4] = (_Float16)v1.x; h[5] = (_Float16)v1.y; h[6] = (_Float16)v1.z; h[7] = (_Float16)v1.w;
    return h;
}

__device__ __forceinline__ float ss8(float4 v0, float4 v1) {
    return v0.x*v0.x + v0.y*v0.y + v0.z*v0.z + v0.w*v0.w
         + v1.x*v1.x + v1.y*v1.y + v1.z*v1.z + v1.w*v1.w;
}

// superpanel k: tiles 0..lenA-1 are (br=k, bc=k+t); rest are (br=63-k, bc=63-k+t-lenA)
__device__ __forceinline__ void dec_sp(int k, int t, int lenA, int& br, int& bc) {
    if (t < lenA) { br = k;      bc = k + t; }
    else          { br = 63 - k; bc = 63 - k + (t - lenA); }
}

// ---- k_prep: anchors + xh (fp16) + sq + ap + GLOBAL e-lists ---------------------------
// (egrid pads are NOT initialized; k_main masks them via ecnt during the LDS copy)

__launch_bounds__(256)
__global__ void k_prep(const float* __restrict__ x, const int* __restrict__ labels,
                       _Float16* __restrict__ xh, float* __restrict__ sq,
                       int* __restrict__ anchorg, float* __restrict__ ap,
                       int* __restrict__ ecnt, float* __restrict__ egrid,
                       float* __restrict__ out) {
    __shared__ int sAnc[C];
    const int tid = threadIdx.x;
    if (blockIdx.x == 0 && tid == 0) out[0] = 0.f;
    for (int i = tid; i < C; i += 256) sAnc[i] = INT_MAX;
    __syncthreads();
    const int4* lab4 = (const int4*)labels;
    for (int t = tid; t < N / 4; t += 256) {
        int4 lv = lab4[t];
        int base = 4 * t;
        atomicMin(&sAnc[lv.x], base);
        atomicMin(&sAnc[lv.y], base + 1);
        atomicMin(&sAnc[lv.z], base + 2);
        atomicMin(&sAnc[lv.w], base + 3);
    }
    __syncthreads();
    if (tid < 2) {
        int c = blockIdx.x * 2 + tid;
        int a = sAnc[c];
        anchorg[c] = (a == INT_MAX) ? -1 : a;
    }

    const int r = blockIdx.x * 32 + (tid >> 3);
    const int sub = tid & 7;
    const float4* src = (const float4*)(x + (size_t)r * D) + sub * 4;
    half8* dst = (half8*)(xh + (size_t)r * D) + sub * 2;
    half8 hj[2];
    float ssj = 0.f;
#pragma unroll
    for (int i = 0; i < 2; ++i) {
        float4 v0 = src[2 * i], v1 = src[2 * i + 1];
        hj[i] = cvt8(v0, v1);
        dst[i] = hj[i];
        ssj += ss8(v0, v1);
    }
    ssj += __shfl_xor(ssj, 1); ssj += __shfl_xor(ssj, 2); ssj += __shfl_xor(ssj, 4);

    const int lab = labels[r];
    const int a = sAnc[lab];
    const float4* asrc = (const float4*)(x + (size_t)a * D) + sub * 4;
    float ssa = 0.f, dot = 0.f;
#pragma unroll
    for (int i = 0; i < 2; ++i) {
        float4 a0 = asrc[2 * i], a1 = asrc[2 * i + 1];
        half8 ha = cvt8(a0, a1);
        ssa += ss8(a0, a1);
#pragma unroll
        for (int e = 0; e < 8; ++e) dot = fmaf((float)ha[e], (float)hj[i][e], dot);
    }
    ssa += __shfl_xor(ssa, 1); ssa += __shfl_xor(ssa, 2); ssa += __shfl_xor(ssa, 4);
    dot += __shfl_xor(dot, 1); dot += __shfl_xor(dot, 2); dot += __shfl_xor(dot, 4);
    if (sub == 0) {
        float apv = ssa + ssj - 2.f * dot;
        sq[r] = ssj;
        ap[r] = apv;
        if (r != a) {   // append to the class e-list (anchor itself excluded)
            int slot = atomicAdd(&ecnt[lab], 1);
            if (slot < MAXG) egrid[(size_t)lab * MAXG + slot] = apv + HALFA;
        }
    }
}

// ---- k_main: R12-proven schedule; delta: term1 slot loop software-pipelined -----------
// (8 slots/iter, next-8 prefetched before processing current-8 — hides ds_read_b128
// latency that a runtime-trip-count loop otherwise exposes every iteration).
// __launch_bounds__(512,2): proven no-spill; do NOT tighten (R4/R6 spill disasters).

__launch_bounds__(512, 2)
__global__ void k_main(const _Float16* __restrict__ xh, const int* __restrict__ labels,
                       const int* __restrict__ anchor, const float* __restrict__ sq,
                       const float* __restrict__ ap, const int* __restrict__ ecnt,
                       const float* __restrict__ egrid, float* __restrict__ out) {
    __shared__ __align__(16) _Float16 BsH[GR * SL * 8];   // 33024 B, K-major [granule][row]
    __shared__ __align__(16) float sge[64 * MAXG];        // 12288 B e-lists
    __shared__ float4 rowE[BT];
    __shared__ float4 colE[2][BT];
    __shared__ int   sArow[64];
    __shared__ float sSqA[64];
    __shared__ int   sCnt[64];
    __shared__ float wsum[8];
    half8* Bs = (half8*)BsH;

    const int tid = threadIdx.x;
    const int lane = tid & 63, w = tid >> 6;
    const int m = lane & 31, q = lane >> 5;
    const int sg = tid & 15, sr0 = tid >> 4;   // staging: granule, row base
    float local = 0.f;
    int cnt = 0;                                // hinge slots evaluated (for +h*cnt)

    const int b = blockIdx.x;
    // term1 tile coords (one tile per block: 8 class-panels x 64 j-tiles)
    const int c0 = (b >> 6) * 64, j1 = (b & 63) * BT;
    // term2 walker coords (superpanel k, lane p)
    const int kk_sp = b >> 4, p = b & 15;
    const int lenA = 64 - kk_sp;

    half8 af[8], breg[4];
    floatx16 acc = zerov();

    // ================= phase 0: term1 meta + EPAD-masked e-list copy + B prefetch =======
    if (tid < 64) {
        int c = c0 + tid;
        int a = anchor[c];
        int ar = (a < 0) ? 0 : a;          // dummy (absent class has cnt 0)
        sArow[tid] = ar;
        sSqA[tid] = sq[ar];
        int n = ecnt[c];
        sCnt[tid] = (n > MAXG) ? MAXG : n;
    }
    {   // e-list copy; pads (uninitialized in egrid) forced to EPAD
        const float4* srcv = (const float4*)(egrid + (size_t)c0 * MAXG);
        float4* dstv = (float4*)sge;
#pragma unroll
        for (int rep = 0; rep < 2; ++rep) {
            int idx = tid + rep * 512;
            if (idx < 64 * (MAXG / 4)) {
                int cls = idx / (MAXG / 4);
                int sb = (idx % (MAXG / 4)) * 4;
                int n = ecnt[c0 + cls]; n = (n > MAXG) ? MAXG : n;
                float4 v = srcv[idx];
                v.x = (sb + 0 < n) ? v.x : EPAD;
                v.y = (sb + 1 < n) ? v.y : EPAD;
                v.z = (sb + 2 < n) ? v.z : EPAD;
                v.w = (sb + 3 < n) ? v.w : EPAD;
                dstv[idx] = v;
            }
        }
    }
#pragma unroll
    for (int i = 0; i < 4; ++i)
        breg[i] = *((const half8*)(xh + (size_t)(j1 + sr0 + 32 * i) * D) + sg);
    if (tid < BT) {
        int j = j1 + tid;
        colE[0][tid] = make_float4(sq[j], __int_as_float(labels[j]), 0.f, 0.f);
    }
    __syncthreads();

    // ================= phase 1: term1 MFMA =================
    {   // gathered anchor rows; 2 row-groups x 4 col-groups
        int arow = sArow[(w >> 2) * 32 + m];
        const half8* aptr = (const half8*)(xh + (size_t)arow * D) + q;
#pragma unroll
        for (int k = 0; k < 8; ++k) af[k] = aptr[2 * k];
    }
#pragma unroll
    for (int i = 0; i < 4; ++i)
        Bs[sg * SL + sr0 + 32 * i] = breg[i];
    __syncthreads();

#pragma unroll
    for (int k = 0; k < 8; ++k) {
        half8 b0 = Bs[(2 * k + q) * SL + (w & 3) * 32 + m];
        acc = __builtin_amdgcn_mfma_f32_32x32x16_f16(af[k], b0, acc, 0, 0, 0);
    }

    // ================= phase 2: prefetch first term2 tile (hides under epilogue) =======
    int br0, bc0;
    dec_sp(kk_sp, p, lenA, br0, bc0);
    {
        const half8* aptr = (const half8*)(xh + (size_t)(br0 * BT + (w >> 1) * 32 + m) * D) + q;
#pragma unroll
        for (int k = 0; k < 8; ++k) af[k] = aptr[2 * k];   // af dead after term1 MFMA
#pragma unroll
        for (int i = 0; i < 4; ++i)
            breg[i] = *((const half8*)(xh + (size_t)(bc0 * BT + sr0 + 32 * i) * D) + sg);
        if (tid < BT) {
            int i = br0 * BT + tid;
            int li = labels[i]; int a = anchor[li];
            float sqi = sq[i];
            float e2 = (i == a) ? -1e30f : ap[i] + HALFA - sqi;
            rowE[tid] = make_float4(e2, __int_as_float(li), sqi, 0.f);
        } else if (tid < 2 * BT) {
            int j = bc0 * BT + tid - BT;
            int lj = labels[j]; int a = anchor[lj];
            float sqj = sq[j];
            float e2 = (j == a) ? -1e30f : ap[j] + HALFA - sqj;
            colE[1][tid - BT] = make_float4(e2, __int_as_float(lj), sqj, 0.f);
        }
    }

    // ================= phase 3: term1 hinge epilogue (pipelined slot loop) =============
    __builtin_amdgcn_s_setprio(1);
    {
        float4 cj = colE[0][(w & 3) * 32 + m];
        float sqj = cj.x; int labj = __float_as_int(cj.y);
#pragma unroll
        for (int rr = 0; rr < 16; ++rr) {
            int row = (w >> 2) * 32 + (rr & 3) + 8 * (rr >> 2) + 4 * q;
            float Dv = fmaf(-2.f, acc[rr], sSqA[row] + sqj);
            Dv = (labj != c0 + row) ? Dv : DMASK;         // fold label mask into base
            int nf = (sCnt[row] + 7) & ~7;                // 8-wide; pads contribute 0
            cnt += nf;
            const float* base = &sge[row * MAXG];
            float4 e0 = *(const float4*)(base);
            float4 e1 = *(const float4*)(base + 4);
            for (int gb = 0; gb < nf; gb += 8) {
                float4 n0 = e0, n1 = e1;
                if (gb + 8 < nf) {                        // prefetch next 8 slots
                    n0 = *(const float4*)(base + gb + 8);
                    n1 = *(const float4*)(base + gb + 12);
                }
                float u;
                u = e0.x - Dv; local += (__builtin_fabsf(u) < HALFA) ? u : -HALFA;
                u = e0.y - Dv; local += (__builtin_fabsf(u) < HALFA) ? u : -HALFA;
                u = e0.z - Dv; local += (__builtin_fabsf(u) < HALFA) ? u : -HALFA;
                u = e0.w - Dv; local += (__builtin_fabsf(u) < HALFA) ? u : -HALFA;
                u = e1.x - Dv; local += (__builtin_fabsf(u) < HALFA) ? u : -HALFA;
                u = e1.y - Dv; local += (__builtin_fabsf(u) < HALFA) ? u : -HALFA;
                u = e1.z - Dv; local += (__builtin_fabsf(u) < HALFA) ? u : -HALFA;
                u = e1.w - Dv; local += (__builtin_fabsf(u) < HALFA) ? u : -HALFA;
                e0 = n0; e1 = n1;
            }
        }
    }
    __builtin_amdgcn_s_setprio(0);
    __syncthreads();   // rowE/colE[1] ready; Bs free for the walker

    // ================= phase 4: term2 superpanel walker =================
    {
        const int wr = w >> 1, wc = w & 1;     // 4 row-groups x 2 col-groups
        int cbuf = 1, cur_br = br0;

        for (int t = p; t < 65; t += SPB) {
            int br, bc; dec_sp(kk_sp, t, lenA, br, bc);
            const int i0 = br * BT;
            const bool diag = (br == bc);

            if (br != cur_br) {                 // at most one seam per block
                cur_br = br;
                const half8* aptr = (const half8*)(xh + (size_t)(i0 + wr * 32 + m) * D) + q;
#pragma unroll
                for (int k8 = 0; k8 < 8; ++k8) af[k8] = aptr[2 * k8];
                if (tid < BT) {
                    int i = i0 + tid;
                    int li = labels[i]; int a = anchor[li];
                    float sqi = sq[i];
                    float e2 = (i == a) ? -1e30f : ap[i] + HALFA - sqi;
                    rowE[tid] = make_float4(e2, __int_as_float(li), sqi, 0.f);
                }
            }

#pragma unroll
            for (int i = 0; i < 4; ++i)
                Bs[sg * SL + sr0 + 32 * i] = breg[i];
            __syncthreads();

            if (t + SPB < 65) {                 // prefetch next tile
                int brn, bcn; dec_sp(kk_sp, t + SPB, lenA, brn, bcn);
                int j0n = bcn * BT;
#pragma unroll
                for (int i = 0; i < 4; ++i)
                    breg[i] = *((const half8*)(xh + (size_t)(j0n + sr0 + 32 * i) * D) + sg);
                if (tid < BT) {
                    int j = j0n + tid;
                    int lj = labels[j]; int a = anchor[lj];
                    float sqj = sq[j];
                    float e2 = (j == a) ? -1e30f : ap[j] + HALFA - sqj;
                    colE[cbuf ^ 1][tid] = make_float4(e2, __int_as_float(lj), sqj, 0.f);
                }
            }

            __builtin_amdgcn_s_setprio(1);
            floatx16 acc0 = zerov(), acc1 = zerov();
#pragma unroll
            for (int k8 = 0; k8 < 8; ++k8) {
                half8 b0 = Bs[(2 * k8 + q) * SL + wc * 64 + m];
                half8 b1 = Bs[(2 * k8 + q) * SL + wc * 64 + 32 + m];
                acc0 = __builtin_amdgcn_mfma_f32_32x32x16_f16(af[k8], b0, acc0, 0, 0, 0);
                acc1 = __builtin_amdgcn_mfma_f32_32x32x16_f16(af[k8], b1, acc1, 0, 0, 0);
            }

            float sqjv[2], e2j[2]; int labj[2];
            { float4 cj = colE[cbuf][wc * 64 + m];      e2j[0] = cj.x; labj[0] = __float_as_int(cj.y); sqjv[0] = cj.z; }
            { float4 cj = colE[cbuf][wc * 64 + 32 + m]; e2j[1] = cj.x; labj[1] = __float_as_int(cj.y); sqjv[1] = cj.z; }

#pragma unroll
            for (int rr = 0; rr < 16; ++rr) {
                int row = wr * 32 + (rr & 3) + 8 * (rr >> 2) + 4 * q;
                float4 re = rowE[row];
                float e2i = re.x, sqi = re.z;
                int labi = __float_as_int(re.y);
#pragma unroll
                for (int tn = 0; tn < 2; ++tn) {
                    float dot = (tn == 0) ? acc0[rr] : acc1[rr];
                    bool ne = (labi != labj[tn]);
                    float u2 = fmaf(2.f, dot, e2i - sqjv[tn]);
                    local += (ne & (__builtin_fabsf(u2) < HALFA)) ? u2 : -HALFA;
                    if (!diag) {
                        float u2b = fmaf(2.f, dot, e2j[tn] - sqi);
                        local += (ne & (__builtin_fabsf(u2b) < HALFA)) ? u2b : -HALFA;
                    }
                }
            }
            __builtin_amdgcn_s_setprio(0);
            cnt += diag ? 32 : 64;
            cbuf ^= 1;
            __syncthreads();
        }
    }

    // compensation for the -HALFA branchless accumulation, then block reduce
    local += HALFA * (float)cnt;
#pragma unroll
    for (int off = 32; off; off >>= 1) local += __shfl_down(local, off);
    if (lane == 0) wsum[w] = local;
    __syncthreads();
    if (tid == 0) {
        float s = 0.f;
#pragma unroll
        for (int i = 0; i < 8; ++i) s += wsum[i];
        atomicAdd(out, s);
    }
}

// ---------------- launch ----------------

extern "C" void kernel_launch(void* const* d_in, const int* in_sizes, int n_in,
                              void* d_out, int out_size, void* d_ws, size_t ws_size,
                              hipStream_t stream) {
    const float* x = (const float*)d_in[0];
    const int* labels = (const int*)d_in[1];
    float* out = (float*)d_out;

    char* p = (char*)d_ws;
    int* anchor = (int*)p;        p += C * 4;
    float* sq = (float*)p;        p += N * 4;
    float* ap = (float*)p;        p += N * 4;
    int* ecnt = (int*)p;          p += C * 4;
    float* egrid = (float*)p;     p += (size_t)C * MAXG * 4;
    p = (char*)(((uintptr_t)p + 255) & ~(uintptr_t)255);
    _Float16* xh = (_Float16*)p;  // N*D*2 = 2 MB

    hipMemsetAsync(ecnt, 0, C * 4, stream);   // egrid memset not needed (masked copy)
    k_prep<<<N / 32, 256, 0, stream>>>(x, labels, xh, sq, anchor, ap, ecnt, egrid, out);
    k_main<<<GRID, 512, 0, stream>>>(xh, labels, anchor, sq, ap, ecnt, egrid, out);
}